// Round 6
// baseline (222.920 us; speedup 1.0000x reference)
//
#include <hip/hip_runtime.h>
#include <math.h>

// Problem constants
#define BB 4
#define SS 4096
#define DD 64
#define HH 16
#define PI_C 3.1415f

// ---------------------------------------------------------------------------
// ws layout (bytes): unchanged from round 5
//   0        : pkv   fp32 [8][64bh][z*64+x]   8,388,608   (phase1 partials)
//              pden  fp32 [4][b][s][64]      16,777,216   (OVERLAY after k_reduce)
//   8388608  : pkvs  fp32 [8][64bh][z*64+x]   8,388,608
//   16777216 : pks   fp32 [8][64bh][128]        262,144
//   17039360 : kvb   bf16 [64bh][z*64+x]        524,288
//   17563648 : kvsb  bf16                       524,288
//   18087936 : ksums fp32 [64bh][128]            32,768
//   18120704 : wT    bf16 wq|wk|wv|wd x 65536   524,288
// ---------------------------------------------------------------------------

typedef __attribute__((ext_vector_type(8))) short short8;   // bf16 MFMA operand
typedef __attribute__((ext_vector_type(4))) float f32x4;    // MFMA C/D frag

#define MFMA(a, b, c) __builtin_amdgcn_mfma_f32_16x16x32_bf16(a, b, c, 0, 0, 0)

__device__ __forceinline__ short f2bf(float f) {
    union { float f; unsigned u; } v; v.f = f;
    unsigned r = v.u + 0x7FFFu + ((v.u >> 16) & 1u);   // RNE
    return (short)(r >> 16);
}
__device__ __forceinline__ short8 cvt8(float4 a, float4 b) {
    short8 r;
    r[0] = f2bf(a.x); r[1] = f2bf(a.y); r[2] = f2bf(a.z); r[3] = f2bf(a.w);
    r[4] = f2bf(b.x); r[5] = f2bf(b.y); r[6] = f2bf(b.z); r[7] = f2bf(b.w);
    return r;
}
__device__ __forceinline__ float elu1(float x) { return x > 0.f ? x + 1.f : __expf(x); }
__device__ __forceinline__ void st4(short* p, short a, short b, short c, short d) {
    union { uint2 u; short s[4]; } x;
    x.s[0] = a; x.s[1] = b; x.s[2] = c; x.s[3] = d;
    *reinterpret_cast<uint2*>(p) = x.u;
}
// 4 real bf16 values in k-slots j=0..3, zeros in j=4..7 (zero-padded K trick:
// both operands put real k at slot 8Q+j, j<4 -> products over matching slots).
__device__ __forceinline__ short8 pack4pad(float a, float b, float c, float d) {
    short8 r;
    r[0] = f2bf(a); r[1] = f2bf(b); r[2] = f2bf(c); r[3] = f2bf(d);
    r[4] = 0; r[5] = 0; r[6] = 0; r[7] = 0;
    return r;
}
__device__ __forceinline__ short8 pad8(uint2 p) {
    union { uint2 u; short s[4]; } x; x.u = p;
    short8 r;
    r[0] = x.s[0]; r[1] = x.s[1]; r[2] = x.s[2]; r[3] = x.s[3];
    r[4] = 0; r[5] = 0; r[6] = 0; r[7] = 0;
    return r;
}

// ---------------------------------------------------------------------------
// Transpose + bf16-convert weights into per-head [out_col][in_dim] layout.
__global__ __launch_bounds__(256) void k_prep(
    const float* __restrict__ wq, const float* __restrict__ wk,
    const float* __restrict__ wv, const float* __restrict__ wd,
    short* __restrict__ dst)
{
    const int h = blockIdx.x, y = blockIdx.y, t = threadIdx.x;
    const float* src = (y == 0) ? wq : (y == 1) ? wk : (y == 2) ? wv : wd;
    const int rs = (y < 3) ? 1024 : 64;
    const size_t srcbase = (y < 3) ? (size_t)(h * 64) : (size_t)(h * 4096);
    short* dm = dst + (size_t)y * 65536 + (size_t)h * 4096;
#pragma unroll
    for (int j = 0; j < 4; ++j) {
        int idx = j * 1024 + t * 4;
        int r = idx >> 6, c = idx & 63;
        float4 v = *reinterpret_cast<const float4*>(src + (size_t)r * rs + srcbase + c);
        dm[(c + 0) * 64 + r] = f2bf(v.x);
        dm[(c + 1) * 64 + r] = f2bf(v.y);
        dm[(c + 2) * 64 + r] = f2bf(v.z);
        dm[(c + 3) * 64 + r] = f2bf(v.w);
    }
}

// ---------------------------------------------------------------------------
// Phase 1: fully wave-independent main loop (no barriers, no LDS in loop).
// Wave w owns s-range [chunk*512 + w*128, +128) in 8 chunks of 16 s.
// Per chunk: proj K/V (full-K 16x16x32 MFMA) -> C-frags used DIRECTLY as
// zero-padded K=16 operands of the kv/kvs GEMM (C-layout == operand layout).
// End-of-block: owner-rotation LDS reduce of the 4 waves' kv/kvs partials.
__global__ __launch_bounds__(256, 2) void k_phase1(
    const float* __restrict__ key, const float* __restrict__ value,
    const float* __restrict__ wk_b, const float* __restrict__ wv_b,
    const short* __restrict__ wkTb, const short* __restrict__ wvTb,
    float* __restrict__ pkv, float* __restrict__ pkvs,
    float* __restrict__ pks)
{
    const int chunk = blockIdx.x, h = blockIdx.y, b = blockIdx.z;
    const int t = threadIdx.x, w = t >> 6, l = t & 63;
    const int l15 = l & 15, q8 = (l >> 4) * 8, q4 = (l >> 4) * 4;

    __shared__ float sc[4][1088];    // 16 z-rows x 64 x, stride 68
    __shared__ float ksr[4][128];

    const short* wkh = wkTb + (size_t)h * 4096;
    const short* wvh = wvTb + (size_t)h * 4096;

    float bk4[4], bv4[4];
#pragma unroll
    for (int nt = 0; nt < 4; ++nt) {
        bk4[nt] = wk_b[h * 64 + nt * 16 + l15];
        bv4[nt] = wv_b[h * 64 + nt * 16 + l15];
    }

    f32x4 ckv[4][4], ckvs[4][4];
#pragma unroll
    for (int mt = 0; mt < 4; ++mt)
#pragma unroll
        for (int nt = 0; nt < 4; ++nt) {
            ckv[mt][nt]  = (f32x4){0.f, 0.f, 0.f, 0.f};
            ckvs[mt][nt] = (f32x4){0.f, 0.f, 0.f, 0.f};
        }
    float aks[4] = {0.f, 0.f, 0.f, 0.f}, akss[4] = {0.f, 0.f, 0.f, 0.f};

    const int sbase = chunk * 512 + w * 128;

    for (int it = 0; it < 8; ++it) {
        const int s0 = sbase + it * 16;
        float sn[4];
#pragma unroll
        for (int r = 0; r < 4; ++r)
            sn[r] = __sinf(PI_C * (float)(s0 + q4 + r) * (1.f / 4096.f));

        // ---- K path: proj D[m=s][n=x] -> elu -> kop (zero-padded k=s frags) ----
        short8 kop[4];
        {
            const float* kp = key + ((size_t)b * SS + s0 + l15) * 64 + q8;
            float4 f0 = *reinterpret_cast<const float4*>(kp);
            float4 f1 = *reinterpret_cast<const float4*>(kp + 4);
            float4 f2 = *reinterpret_cast<const float4*>(kp + 32);
            float4 f3 = *reinterpret_cast<const float4*>(kp + 36);
            short8 a0 = cvt8(f0, f1), a1 = cvt8(f2, f3);
            f32x4 cK[4];
#pragma unroll
            for (int nt = 0; nt < 4; ++nt) cK[nt] = (f32x4){0.f, 0.f, 0.f, 0.f};
#pragma unroll
            for (int nt = 0; nt < 4; ++nt) {
                short8 b0 = *reinterpret_cast<const short8*>(wkh + (nt * 16 + l15) * 64 + q8);
                short8 b1 = *reinterpret_cast<const short8*>(wkh + (nt * 16 + l15) * 64 + 32 + q8);
                cK[nt] = MFMA(a0, b0, cK[nt]);
                cK[nt] = MFMA(a1, b1, cK[nt]);
            }
#pragma unroll
            for (int nt = 0; nt < 4; ++nt) {
                float k0 = elu1(cK[nt][0] + bk4[nt]);
                float k1 = elu1(cK[nt][1] + bk4[nt]);
                float k2 = elu1(cK[nt][2] + bk4[nt]);
                float k3 = elu1(cK[nt][3] + bk4[nt]);
                aks[nt]  += k0 + k1 + k2 + k3;
                akss[nt] += k0 * sn[0] + k1 * sn[1] + k2 * sn[2] + k3 * sn[3];
                kop[nt] = pack4pad(k0, k1, k2, k3);
            }
        }
        // ---- V path ----
        short8 vop[4], vsop[4];
        {
            const float* vp = value + ((size_t)b * SS + s0 + l15) * 64 + q8;
            float4 f0 = *reinterpret_cast<const float4*>(vp);
            float4 f1 = *reinterpret_cast<const float4*>(vp + 4);
            float4 f2 = *reinterpret_cast<const float4*>(vp + 32);
            float4 f3 = *reinterpret_cast<const float4*>(vp + 36);
            short8 a0 = cvt8(f0, f1), a1 = cvt8(f2, f3);
            f32x4 cV[4];
#pragma unroll
            for (int nt = 0; nt < 4; ++nt) cV[nt] = (f32x4){0.f, 0.f, 0.f, 0.f};
#pragma unroll
            for (int nt = 0; nt < 4; ++nt) {
                short8 b0 = *reinterpret_cast<const short8*>(wvh + (nt * 16 + l15) * 64 + q8);
                short8 b1 = *reinterpret_cast<const short8*>(wvh + (nt * 16 + l15) * 64 + 32 + q8);
                cV[nt] = MFMA(a0, b0, cV[nt]);
                cV[nt] = MFMA(a1, b1, cV[nt]);
            }
#pragma unroll
            for (int nt = 0; nt < 4; ++nt) {
                float v0 = cV[nt][0] + bv4[nt];
                float v1 = cV[nt][1] + bv4[nt];
                float v2 = cV[nt][2] + bv4[nt];
                float v3 = cV[nt][3] + bv4[nt];
                vop[nt]  = pack4pad(v0, v1, v2, v3);
                vsop[nt] = pack4pad(v0 * sn[0], v1 * sn[1], v2 * sn[2], v3 * sn[3]);
            }
        }
        // ---- kv / kvs GEMM: D[m=z][n=x], k=s (16 real, zero-padded) ----
#pragma unroll
        for (int mt = 0; mt < 4; ++mt)
#pragma unroll
            for (int nt = 0; nt < 4; ++nt) {
                ckv[mt][nt]  = MFMA(vop[mt],  kop[nt], ckv[mt][nt]);
                ckvs[mt][nt] = MFMA(vsop[mt], kop[nt], ckvs[mt][nt]);
            }
    }

    // ---- owner-rotation cross-wave reduce: kv then kvs ----
#pragma unroll
    for (int rd = 1; rd <= 3; ++rd) {
        const int dst = (w + rd) & 3, src = (w + 4 - rd) & 3;
#pragma unroll
        for (int mt = 0; mt < 4; ++mt) if (mt == dst)
#pragma unroll
            for (int nt = 0; nt < 4; ++nt)
#pragma unroll
                for (int r = 0; r < 4; ++r)
                    sc[w][(q4 + r) * 68 + nt * 16 + l15] = ckv[mt][nt][r];
        __syncthreads();
#pragma unroll
        for (int mt = 0; mt < 4; ++mt) if (mt == w)
#pragma unroll
            for (int nt = 0; nt < 4; ++nt)
#pragma unroll
                for (int r = 0; r < 4; ++r)
                    ckv[mt][nt][r] += sc[src][(q4 + r) * 68 + nt * 16 + l15];
        __syncthreads();
    }
#pragma unroll
    for (int rd = 1; rd <= 3; ++rd) {
        const int dst = (w + rd) & 3, src = (w + 4 - rd) & 3;
#pragma unroll
        for (int mt = 0; mt < 4; ++mt) if (mt == dst)
#pragma unroll
            for (int nt = 0; nt < 4; ++nt)
#pragma unroll
                for (int r = 0; r < 4; ++r)
                    sc[w][(q4 + r) * 68 + nt * 16 + l15] = ckvs[mt][nt][r];
        __syncthreads();
#pragma unroll
        for (int mt = 0; mt < 4; ++mt) if (mt == w)
#pragma unroll
            for (int nt = 0; nt < 4; ++nt)
#pragma unroll
                for (int r = 0; r < 4; ++r)
                    ckvs[mt][nt][r] += sc[src][(q4 + r) * 68 + nt * 16 + l15];
        __syncthreads();
    }

    // ---- commit: wave w owns z-rows [w*16,+16), coalesced stores ----
    const size_t pbase = ((size_t)(chunk * 64) + b * HH + h) * 4096;
#pragma unroll
    for (int mt = 0; mt < 4; ++mt) if (mt == w)
#pragma unroll
        for (int nt = 0; nt < 4; ++nt)
#pragma unroll
            for (int r = 0; r < 4; ++r) {
                const int z = w * 16 + q4 + r, x = nt * 16 + l15;
                pkv [pbase + z * 64 + x] = ckv[mt][nt][r];
                pkvs[pbase + z * 64 + x] = ckvs[mt][nt][r];
            }
    // ---- ksums: cross-quad shuffle + cross-wave LDS ----
#pragma unroll
    for (int nt = 0; nt < 4; ++nt) {
        aks[nt]  += __shfl_xor(aks[nt], 16);  aks[nt]  += __shfl_xor(aks[nt], 32);
        akss[nt] += __shfl_xor(akss[nt], 16); akss[nt] += __shfl_xor(akss[nt], 32);
    }
    if (l < 16) {
#pragma unroll
        for (int nt = 0; nt < 4; ++nt) {
            ksr[w][nt * 16 + l]      = aks[nt];
            ksr[w][64 + nt * 16 + l] = akss[nt];
        }
    }
    __syncthreads();
    if (t < 128)
        pks[((size_t)(chunk * 64) + b * HH + h) * 128 + t] =
            ksr[0][t] + ksr[1][t] + ksr[2][t] + ksr[3][t];
}

// ---------------------------------------------------------------------------
// Reduce 8 chunk partials -> bf16 kv/kvs + fp32 ksums. (unchanged)
__global__ __launch_bounds__(256) void k_reduce(
    const float* __restrict__ pkv, const float* __restrict__ pkvs,
    const float* __restrict__ pks,
    short* __restrict__ kvb, short* __restrict__ kvsb,
    float* __restrict__ ksums)
{
    const int blk = blockIdx.x, t = threadIdx.x;
    if (blk < 512) {
        const float* src = (blk < 256) ? pkv : pkvs;
        short* dst = (blk < 256) ? kvb : kvsb;
        const int o4 = (blk & 255) * 256 + t;
        float4 s = make_float4(0.f, 0.f, 0.f, 0.f);
#pragma unroll
        for (int c = 0; c < 8; ++c) {
            float4 v = reinterpret_cast<const float4*>(src + (size_t)c * 262144)[o4];
            s.x += v.x; s.y += v.y; s.z += v.z; s.w += v.w;
        }
        st4(dst + (size_t)o4 * 4, f2bf(s.x), f2bf(s.y), f2bf(s.z), f2bf(s.w));
    } else {
        const int g = (blk - 512) * 256 + t;
        float4 s = make_float4(0.f, 0.f, 0.f, 0.f);
#pragma unroll
        for (int c = 0; c < 8; ++c) {
            float4 v = reinterpret_cast<const float4*>(pks + (size_t)c * 8192)[g];
            s.x += v.x; s.y += v.y; s.z += v.z; s.w += v.w;
        }
        reinterpret_cast<float4*>(ksums)[g] = s;
    }
}

// ---------------------------------------------------------------------------
// k_attn: grid (64 s-tiles of 64 rows, 4 head-groups, 4 b). Wave w = head
// g*4+w, processes 4 s-tiles of 16. All stages flipped so that each MFMA's
// C-frags feed the next stage directly in registers (C-layout == operand
// layout, contraction over producer rows; K=16 stages zero-padded).
// No barriers in the loop; one barrier + cooperative 4-head sum at the end.
__global__ __launch_bounds__(256, 2) void k_attn(
    const float* __restrict__ query, const float* __restrict__ wq_b,
    const short* __restrict__ wqTb,
    const short* __restrict__ kvb, const short* __restrict__ kvsb,
    const float* __restrict__ ksums,
    const short* __restrict__ wdTb,
    float* __restrict__ pden)
{
    const int st = blockIdx.x, g = blockIdx.y, b = blockIdx.z;
    const int s0 = st * 64;
    const int t = threadIdx.x, w = t >> 6, l = t & 63;
    const int l15 = l & 15, q8 = (l >> 4) * 8, q4 = (l >> 4) * 4;
    const int h = g * 4 + w;
    const size_t bh = (size_t)(b * HH + h);

    __shared__ float sred[4][64 * 68];   // [wave][s*68 + c]

    // ---- wave-resident operand fragments ----
    const short* wqh = wqTb + (size_t)h * 4096;
    short8 awq[2][4];                    // A of q-proj: [k-half][x-tile]
#pragma unroll
    for (int kh = 0; kh < 2; ++kh)
#pragma unroll
        for (int nt = 0; nt < 4; ++nt)
            awq[kh][nt] = *reinterpret_cast<const short8*>(
                wqh + (nt * 16 + l15) * 64 + kh * 32 + q8);

    uint2 akv[4][4], akvs[4][4];         // A of num: [z-tile][x-subtile], 4 bf16
    {
        const short* kvh  = kvb  + bh * 4096;
        const short* kvsh = kvsb + bh * 4096;
#pragma unroll
        for (int zt = 0; zt < 4; ++zt)
#pragma unroll
            for (int ks = 0; ks < 4; ++ks) {
                akv[zt][ks]  = *reinterpret_cast<const uint2*>(
                    kvh  + (zt * 16 + l15) * 64 + ks * 16 + q4);
                akvs[zt][ks] = *reinterpret_cast<const uint2*>(
                    kvsh + (zt * 16 + l15) * 64 + ks * 16 + q4);
            }
    }
    uint2 awd[4][4];                     // A of dense: [c-tile][z-subtile]
    {
        const short* wdh = wdTb + (size_t)h * 4096;
#pragma unroll
        for (int ct = 0; ct < 4; ++ct)
#pragma unroll
            for (int zs = 0; zs < 4; ++zs)
                awd[ct][zs] = *reinterpret_cast<const uint2*>(
                    wdh + (ct * 16 + l15) * 64 + zs * 16 + q4);
    }
    float bqv[16], ksx[16], kssx[16];    // per-lane x = nt*16 + q4 + r
#pragma unroll
    for (int nt = 0; nt < 4; ++nt)
#pragma unroll
        for (int r = 0; r < 4; ++r) {
            const int x = nt * 16 + q4 + r;
            bqv[nt * 4 + r]  = wq_b[h * 64 + x];
            ksx[nt * 4 + r]  = ksums[bh * 128 + x];
            kssx[nt * 4 + r] = ksums[bh * 128 + 64 + x];
        }

    for (int ms = 0; ms < 4; ++ms) {
        const int srow = s0 + ms * 16 + l15;   // this lane's s (n-index)
        // ---- q-proj (flipped): D[m=x][n=s] = wq^T . q^T ----
        short8 qb0, qb1;
        {
            const float* qp = query + ((size_t)b * SS + srow) * 64 + q8;
            float4 f0 = *reinterpret_cast<const float4*>(qp);
            float4 f1 = *reinterpret_cast<const float4*>(qp + 4);
            float4 f2 = *reinterpret_cast<const float4*>(qp + 32);
            float4 f3 = *reinterpret_cast<const float4*>(qp + 36);
            qb0 = cvt8(f0, f1);
            qb1 = cvt8(f2, f3);
        }
        f32x4 cq[4];
#pragma unroll
        for (int nt = 0; nt < 4; ++nt) cq[nt] = (f32x4){0.f, 0.f, 0.f, 0.f};
#pragma unroll
        for (int nt = 0; nt < 4; ++nt) {
            cq[nt] = MFMA(awq[0][nt], qb0, cq[nt]);
            cq[nt] = MFMA(awq[1][nt], qb1, cq[nt]);
        }
        // ---- elu + denominator (per-lane s) + pack q'^T operand frags ----
        const float ph = PI_C * (float)srow * (1.f / 4096.f);
        const float cc = __cosf(ph) + __sinf(ph);
        float dp = 0.f;
        short8 qop[4];
#pragma unroll
        for (int nt = 0; nt < 4; ++nt) {
            float qv0 = elu1(cq[nt][0] + bqv[nt * 4 + 0]);
            float qv1 = elu1(cq[nt][1] + bqv[nt * 4 + 1]);
            float qv2 = elu1(cq[nt][2] + bqv[nt * 4 + 2]);
            float qv3 = elu1(cq[nt][3] + bqv[nt * 4 + 3]);
            dp += qv0 * fmaf(cc, kssx[nt * 4 + 0], ksx[nt * 4 + 0]);
            dp += qv1 * fmaf(cc, kssx[nt * 4 + 1], ksx[nt * 4 + 1]);
            dp += qv2 * fmaf(cc, kssx[nt * 4 + 2], ksx[nt * 4 + 2]);
            dp += qv3 * fmaf(cc, kssx[nt * 4 + 3], ksx[nt * 4 + 3]);
            qop[nt] = pack4pad(qv0, qv1, qv2, qv3);
        }
        dp += __shfl_xor(dp, 16);
        dp += __shfl_xor(dp, 32);
        const float invd = 1.f / (dp + 1e-5f);

        // ---- num (flipped): D[m=z][n=s], contraction k=x in 4 subtiles ----
        f32x4 co[4], cs[4];
#pragma unroll
        for (int zt = 0; zt < 4; ++zt) {
            co[zt] = (f32x4){0.f, 0.f, 0.f, 0.f};
            cs[zt] = (f32x4){0.f, 0.f, 0.f, 0.f};
        }
#pragma unroll
        for (int zt = 0; zt < 4; ++zt)
#pragma unroll
            for (int ks = 0; ks < 4; ++ks) {
                co[zt] = MFMA(pad8(akv[zt][ks]),  qop[ks], co[zt]);
                cs[zt] = MFMA(pad8(akvs[zt][ks]), qop[ks], cs[zt]);
            }
        // ---- combine + pack O^T operand frags ----
        short8 oop[4];
#pragma unroll
        for (int zt = 0; zt < 4; ++zt) {
            float o0 = fmaf(cc, cs[zt][0], co[zt][0]) * invd;
            float o1 = fmaf(cc, cs[zt][1], co[zt][1]) * invd;
            float o2 = fmaf(cc, cs[zt][2], co[zt][2]) * invd;
            float o3 = fmaf(cc, cs[zt][3], co[zt][3]) * invd;
            oop[zt] = pack4pad(o0, o1, o2, o3);
        }
        // ---- dense (flipped): D[m=c][n=s], contraction k=z in 4 subtiles ----
        f32x4 cd[4];
#pragma unroll
        for (int ct = 0; ct < 4; ++ct) cd[ct] = (f32x4){0.f, 0.f, 0.f, 0.f};
#pragma unroll
        for (int ct = 0; ct < 4; ++ct)
#pragma unroll
            for (int zs = 0; zs < 4; ++zs)
                cd[ct] = MFMA(pad8(awd[ct][zs]), oop[zs], cd[ct]);
        // ---- stash dense^T partial: value (c = ct*16+q4+r, s = ms*16+l15) ----
#pragma unroll
        for (int ct = 0; ct < 4; ++ct)
#pragma unroll
            for (int r = 0; r < 4; ++r)
                sred[w][(ms * 16 + l15) * 68 + ct * 16 + q4 + r] = cd[ct][r];
    }
    __syncthreads();

    // ---- cooperative 4-head sum -> pden (group partial) ----
    {
        const int s = t >> 2, c0 = (t & 3) * 16;
        float* outp = pden + (((size_t)(g * BB + b) * SS) + s0 + s) * 64 + c0;
#pragma unroll
        for (int j = 0; j < 4; ++j) {
            float4 a = make_float4(0.f, 0.f, 0.f, 0.f);
#pragma unroll
            for (int w4 = 0; w4 < 4; ++w4) {
                float4 v = *reinterpret_cast<const float4*>(&sred[w4][s * 68 + c0 + j * 4]);
                a.x += v.x; a.y += v.y; a.z += v.z; a.w += v.w;
            }
            *reinterpret_cast<float4*>(outp + j * 4) = a;
        }
    }
}

// ---------------------------------------------------------------------------
// Final: sum the 4 head-group partials + dense bias -> out. (unchanged)
__global__ __launch_bounds__(256) void k_dfinal(
    const float* __restrict__ pden, const float* __restrict__ dense_b,
    float* __restrict__ out)
{
    const int i4 = blockIdx.x * 256 + threadIdx.x;
    const int c4 = i4 & 15;
    const int bb = i4 >> 16;
    const int rem = i4 & 65535;
    float4 s = *reinterpret_cast<const float4*>(dense_b + c4 * 4);
#pragma unroll
    for (int g = 0; g < 4; ++g) {
        float4 v = reinterpret_cast<const float4*>(pden)[(size_t)(g * BB + bb) * 65536 + rem];
        s.x += v.x; s.y += v.y; s.z += v.z; s.w += v.w;
    }
    reinterpret_cast<float4*>(out)[i4] = s;
}

// ---------------------------------------------------------------------------
extern "C" void kernel_launch(void* const* d_in, const int* in_sizes, int n_in,
                              void* d_out, int out_size, void* d_ws, size_t ws_size,
                              hipStream_t stream) {
    const float* query   = (const float*)d_in[0];
    const float* key     = (const float*)d_in[1];
    const float* value   = (const float*)d_in[2];
    // d_in[3] attn_mask unused
    const float* wq_w    = (const float*)d_in[4];
    const float* wq_b    = (const float*)d_in[5];
    const float* wk_w    = (const float*)d_in[6];
    const float* wk_b    = (const float*)d_in[7];
    const float* wv_w    = (const float*)d_in[8];
    const float* wv_b    = (const float*)d_in[9];
    const float* dense_w = (const float*)d_in[10];
    const float* dense_b = (const float*)d_in[11];
    float* out = (float*)d_out;

    char* ws = (char*)d_ws;
    float* pkv   = (float*)(ws);
    float* pkvs  = (float*)(ws + 8388608);
    float* pden  = (float*)(ws);             // overlay: pkv/pkvs dead after k_reduce
    float* pks   = (float*)(ws + 16777216);
    short* kvb   = (short*)(ws + 17039360);
    short* kvsb  = (short*)(ws + 17563648);
    float* ksums = (float*)(ws + 18087936);
    short* wT    = (short*)(ws + 18120704);  // wq|wk|wv|wd, 65536 shorts each
    short* wqTb  = wT;
    short* wkTb  = wT + 65536;
    short* wvTb  = wT + 131072;
    short* wdTb  = wT + 196608;

    hipLaunchKernelGGL(k_prep, dim3(16, 4), dim3(256), 0, stream,
                       wq_w, wk_w, wv_w, dense_w, wT);
    hipLaunchKernelGGL(k_phase1, dim3(8, HH, BB), dim3(256), 0, stream,
                       key, value, wk_b, wv_b, wkTb, wvTb, pkv, pkvs, pks);
    hipLaunchKernelGGL(k_reduce, dim3(520), dim3(256), 0, stream,
                       pkv, pkvs, pks, kvb, kvsb, ksums);
    hipLaunchKernelGGL(k_attn, dim3(SS / 64, 4, BB), dim3(256), 0, stream,
                       query, wq_b, wqTb, kvb, kvsb, ksums, wdTb, pden);
    hipLaunchKernelGGL(k_dfinal, dim3(1024), dim3(256), 0, stream,
                       pden, dense_b, out);
}

// Round 7
// 181.338 us; speedup vs baseline: 1.2293x; 1.2293x over previous
//
#include <hip/hip_runtime.h>
#include <math.h>

// Problem constants
#define BB 4
#define SS 4096
#define DD 64
#define HH 16
#define PI_C 3.1415f

// ---------------------------------------------------------------------------
// ws layout (bytes):
//   0        : wT    bf16 wq|wk|wv|wd x 65536 shorts   524,288
//   524288   : kvb   bf16 [64bh][z*64+x]               524,288
//   1048576  : kvsb  bf16                              524,288
//   1572864  : ksums fp32 [64bh][128]                   32,768
//   1605632  : pkv   fp32 [8][64bh][z*64+x]          8,388,608  (phase1 partials)
//   9994240  : pkvs  fp32                            8,388,608
//   18382848 : pks   fp32 [8][64bh][128]               262,144
//   1605632  : Obuf  bf16 [b][h][s][z]              33,554,432  (OVERLAY: pkv/pkvs/pks
//              dead after k_reduce; Obuf written by k_attn, read by k_dense)
//   total footprint ~35.2 MB
// ---------------------------------------------------------------------------

typedef __attribute__((ext_vector_type(8))) short short8;   // bf16 MFMA operand
typedef __attribute__((ext_vector_type(4))) float f32x4;    // MFMA C/D frag

#define MFMA(a, b, c) __builtin_amdgcn_mfma_f32_16x16x32_bf16(a, b, c, 0, 0, 0)

__device__ __forceinline__ short f2bf(float f) {
    union { float f; unsigned u; } v; v.f = f;
    unsigned r = v.u + 0x7FFFu + ((v.u >> 16) & 1u);   // RNE
    return (short)(r >> 16);
}
__device__ __forceinline__ float bf2f(short s) {
    union { unsigned u; float f; } v;
    v.u = ((unsigned)(unsigned short)s) << 16;
    return v.f;
}
__device__ __forceinline__ short8 cvt8(float4 a, float4 b) {
    short8 r;
    r[0] = f2bf(a.x); r[1] = f2bf(a.y); r[2] = f2bf(a.z); r[3] = f2bf(a.w);
    r[4] = f2bf(b.x); r[5] = f2bf(b.y); r[6] = f2bf(b.z); r[7] = f2bf(b.w);
    return r;
}
__device__ __forceinline__ float elu1(float x) { return x > 0.f ? x + 1.f : __expf(x); }
__device__ __forceinline__ void st4(short* p, short a, short b, short c, short d) {
    union { uint2 u; short s[4]; } x;
    x.s[0] = a; x.s[1] = b; x.s[2] = c; x.s[3] = d;
    *reinterpret_cast<uint2*>(p) = x.u;
}

// ---------------------------------------------------------------------------
// Transpose + bf16-convert weights into per-head [out_col][in_dim] layout.
__global__ __launch_bounds__(256) void k_prep(
    const float* __restrict__ wq, const float* __restrict__ wk,
    const float* __restrict__ wv, const float* __restrict__ wd,
    short* __restrict__ dst)
{
    const int h = blockIdx.x, y = blockIdx.y, t = threadIdx.x;
    const float* src = (y == 0) ? wq : (y == 1) ? wk : (y == 2) ? wv : wd;
    const int rs = (y < 3) ? 1024 : 64;
    const size_t srcbase = (y < 3) ? (size_t)(h * 64) : (size_t)(h * 4096);
    short* dm = dst + (size_t)y * 65536 + (size_t)h * 4096;
#pragma unroll
    for (int j = 0; j < 4; ++j) {
        int idx = j * 1024 + t * 4;
        int r = idx >> 6, c = idx & 63;
        float4 v = *reinterpret_cast<const float4*>(src + (size_t)r * rs + srcbase + c);
        dm[(c + 0) * 64 + r] = f2bf(v.x);
        dm[(c + 1) * 64 + r] = f2bf(v.y);
        dm[(c + 2) * 64 + r] = f2bf(v.z);
        dm[(c + 3) * 64 + r] = f2bf(v.w);
    }
}

// ---------------------------------------------------------------------------
// Phase 1 (unchanged, round-3/5 version): project K,V (MFMA, weight B-frags
// in registers) -> transposed bf16 tiles in LDS -> kv/kvs GEMM with swapped
// operands (A=v, B=k') -> coalesced non-atomic partial stores.
__global__ __launch_bounds__(256, 2) void k_phase1(
    const float* __restrict__ key, const float* __restrict__ value,
    const float* __restrict__ wk_b, const float* __restrict__ wv_b,
    const short* __restrict__ wkTb, const short* __restrict__ wvTb,
    float* __restrict__ pkv, float* __restrict__ pkvs,
    float* __restrict__ pks)
{
    const int chunk = blockIdx.x, h = blockIdx.y, b = blockIdx.z;
    const int t = threadIdx.x, w = t >> 6, l = t & 63;
    const int lane15 = l & 15, q8 = (l >> 4) * 8, q4 = (l >> 4) * 4;

    __shared__ short kT[64 * 72], vT[64 * 72], vsT[64 * 72];   // [x|z][s]
    __shared__ float ssin[512];
    __shared__ float sbk[64], sbv[64];
    __shared__ float sred[512];

    short8 bkf[2][4], bvf[2][4];
    {
        const short* wkh = wkTb + (size_t)h * 4096;
        const short* wvh = wvTb + (size_t)h * 4096;
#pragma unroll
        for (int kss = 0; kss < 2; ++kss)
#pragma unroll
            for (int nt = 0; nt < 4; ++nt) {
                bkf[kss][nt] = *reinterpret_cast<const short8*>(wkh + (nt * 16 + lane15) * 64 + kss * 32 + q8);
                bvf[kss][nt] = *reinterpret_cast<const short8*>(wvh + (nt * 16 + lane15) * 64 + kss * 32 + q8);
            }
    }
    ssin[t]       = __sinf(PI_C * (float)(chunk * 512 + t)       * (1.f / 4096.f));
    ssin[t + 256] = __sinf(PI_C * (float)(chunk * 512 + t + 256) * (1.f / 4096.f));
    if (t < 64) sbk[t] = wk_b[h * 64 + t];
    else if (t < 128) sbv[t - 64] = wv_b[h * 64 + (t - 64)];

    float4 kf0, kf1, kf2, kf3, vf0, vf1, vf2, vf3;
    {
        const size_t g = ((size_t)b * SS + chunk * 512 + w * 16 + lane15) * 64 + q8;
        kf0 = *reinterpret_cast<const float4*>(key + g);
        kf1 = *reinterpret_cast<const float4*>(key + g + 4);
        kf2 = *reinterpret_cast<const float4*>(key + g + 32);
        kf3 = *reinterpret_cast<const float4*>(key + g + 36);
        vf0 = *reinterpret_cast<const float4*>(value + g);
        vf1 = *reinterpret_cast<const float4*>(value + g + 4);
        vf2 = *reinterpret_cast<const float4*>(value + g + 32);
        vf3 = *reinterpret_cast<const float4*>(value + g + 36);
    }

    f32x4 ckv[4], ckvs[4];
#pragma unroll
    for (int i = 0; i < 4; ++i) {
        ckv[i]  = (f32x4){0.f, 0.f, 0.f, 0.f};
        ckvs[i] = (f32x4){0.f, 0.f, 0.f, 0.f};
    }
    float aks = 0.f, akss = 0.f;
    __syncthreads();

    for (int it = 0; it < 8; ++it) {
        const int sbase = it * 64;
        f32x4 ckp[4], cvp[4];
#pragma unroll
        for (int i = 0; i < 4; ++i) {
            ckp[i] = (f32x4){0.f, 0.f, 0.f, 0.f};
            cvp[i] = (f32x4){0.f, 0.f, 0.f, 0.f};
        }
        {
            short8 ak0 = cvt8(kf0, kf1), ak1 = cvt8(kf2, kf3);
            short8 av0 = cvt8(vf0, vf1), av1 = cvt8(vf2, vf3);
#pragma unroll
            for (int nt = 0; nt < 4; ++nt) {
                ckp[nt] = MFMA(ak0, bkf[0][nt], ckp[nt]);
                cvp[nt] = MFMA(av0, bvf[0][nt], cvp[nt]);
                ckp[nt] = MFMA(ak1, bkf[1][nt], ckp[nt]);
                cvp[nt] = MFMA(av1, bvf[1][nt], cvp[nt]);
            }
        }
        const int srel = w * 16 + q4;
#pragma unroll
        for (int nt = 0; nt < 4; ++nt) {
            const int x = nt * 16 + lane15;
            const float bk = sbk[x], bv = sbv[x];
            short ek[4], ev[4], es[4];
#pragma unroll
            for (int r = 0; r < 4; ++r) {
                float kk = elu1(ckp[nt][r] + bk);
                float vv = cvp[nt][r] + bv;
                ek[r] = f2bf(kk);
                ev[r] = f2bf(vv);
                es[r] = f2bf(vv * ssin[sbase + srel + r]);
            }
            st4(&kT [x * 72 + srel], ek[0], ek[1], ek[2], ek[3]);
            st4(&vT [x * 72 + srel], ev[0], ev[1], ev[2], ev[3]);
            st4(&vsT[x * 72 + srel], es[0], es[1], es[2], es[3]);
        }
        __syncthreads();
        if (it < 7) {
            const size_t g = ((size_t)b * SS + chunk * 512 + (it + 1) * 64 + w * 16 + lane15) * 64 + q8;
            kf0 = *reinterpret_cast<const float4*>(key + g);
            kf1 = *reinterpret_cast<const float4*>(key + g + 4);
            kf2 = *reinterpret_cast<const float4*>(key + g + 32);
            kf3 = *reinterpret_cast<const float4*>(key + g + 36);
            vf0 = *reinterpret_cast<const float4*>(value + g);
            vf1 = *reinterpret_cast<const float4*>(value + g + 4);
            vf2 = *reinterpret_cast<const float4*>(value + g + 32);
            vf3 = *reinterpret_cast<const float4*>(value + g + 36);
        }
#pragma unroll
        for (int kstep = 0; kstep < 2; ++kstep) {
            const int so = kstep * 32;
            short8 aV  = *reinterpret_cast<const short8*>(&vT [(w * 16 + lane15) * 72 + so + q8]);
            short8 aVS = *reinterpret_cast<const short8*>(&vsT[(w * 16 + lane15) * 72 + so + q8]);
#pragma unroll
            for (int nt = 0; nt < 4; ++nt) {
                short8 bK = *reinterpret_cast<const short8*>(&kT[(nt * 16 + lane15) * 72 + so + q8]);
                ckv[nt]  = MFMA(aV,  bK, ckv[nt]);
                ckvs[nt] = MFMA(aVS, bK, ckvs[nt]);
            }
        }
        {
            short8 k0 = *reinterpret_cast<const short8*>(&kT[l * 72 + w * 16]);
            short8 k1 = *reinterpret_cast<const short8*>(&kT[l * 72 + w * 16 + 8]);
#pragma unroll
            for (int e = 0; e < 8; ++e) {
                float fa = bf2f(k0[e]), fb = bf2f(k1[e]);
                aks  += fa + fb;
                akss += fa * ssin[sbase + w * 16 + e] + fb * ssin[sbase + w * 16 + 8 + e];
            }
        }
        __syncthreads();
    }

    const int bh = b * HH + h;
    const size_t pbase = ((size_t)(chunk * 64) + bh) * 4096;
#pragma unroll
    for (int nt = 0; nt < 4; ++nt) {
        const int x = nt * 16 + lane15;
#pragma unroll
        for (int r = 0; r < 4; ++r) {
            const int z = w * 16 + q4 + r;
            pkv [pbase + z * 64 + x] = ckv[nt][r];
            pkvs[pbase + z * 64 + x] = ckvs[nt][r];
        }
    }
    sred[t] = aks; sred[256 + t] = akss;
    __syncthreads();
    if (t < 64) {
        pks[((size_t)(chunk * 64) + bh) * 128 + t] =
            sred[t] + sred[64 + t] + sred[128 + t] + sred[192 + t];
    } else if (t < 128) {
        int tt = t - 64;
        pks[((size_t)(chunk * 64) + bh) * 128 + t] =
            sred[256 + tt] + sred[320 + tt] + sred[384 + tt] + sred[448 + tt];
    }
}

// ---------------------------------------------------------------------------
// Reduce 8 chunk partials -> bf16 kv/kvs + fp32 ksums. (unchanged)
__global__ __launch_bounds__(256) void k_reduce(
    const float* __restrict__ pkv, const float* __restrict__ pkvs,
    const float* __restrict__ pks,
    short* __restrict__ kvb, short* __restrict__ kvsb,
    float* __restrict__ ksums)
{
    const int blk = blockIdx.x, t = threadIdx.x;
    if (blk < 512) {
        const float* src = (blk < 256) ? pkv : pkvs;
        short* dst = (blk < 256) ? kvb : kvsb;
        const int o4 = (blk & 255) * 256 + t;
        float4 s = make_float4(0.f, 0.f, 0.f, 0.f);
#pragma unroll
        for (int c = 0; c < 8; ++c) {
            float4 v = reinterpret_cast<const float4*>(src + (size_t)c * 262144)[o4];
            s.x += v.x; s.y += v.y; s.z += v.z; s.w += v.w;
        }
        st4(dst + (size_t)o4 * 4, f2bf(s.x), f2bf(s.y), f2bf(s.z), f2bf(s.w));
    } else {
        const int g = (blk - 512) * 256 + t;
        float4 s = make_float4(0.f, 0.f, 0.f, 0.f);
#pragma unroll
        for (int c = 0; c < 8; ++c) {
            float4 v = reinterpret_cast<const float4*>(pks + (size_t)c * 8192)[g];
            s.x += v.x; s.y += v.y; s.z += v.z; s.w += v.w;
        }
        reinterpret_cast<float4*>(ksums)[g] = s;
    }
}

// ---------------------------------------------------------------------------
// k_attn v7: grid (16 s-blocks of 256 rows, 16 heads, 4 b) = 1024 blocks.
// Block = one (b,h): stage wq/kv/kvs head slices in LDS ONCE (padded stride
// 72), one barrier; then 4 waves x 4 independent 16-row tiles: q-proj -> elu/
// den -> num -> O, with all B-frags from LDS and wave-private LDS transposes.
// Writes per-head O bf16 in [b][h][s][z]; dense handled by k_dense.
__global__ __launch_bounds__(256, 4) void k_attn(
    const float* __restrict__ query, const float* __restrict__ wq_b,
    const short* __restrict__ wqTb,
    const short* __restrict__ kvb, const short* __restrict__ kvsb,
    const float* __restrict__ ksums,
    short* __restrict__ Obuf)
{
    const int sblk = blockIdx.x, h = blockIdx.y, b = blockIdx.z;
    const int t = threadIdx.x, w = t >> 6, l = t & 63;
    const int l15 = l & 15, q8 = (l >> 4) * 8, q4 = (l >> 4) * 4;
    const size_t bh = (size_t)(b * HH + h);

    __shared__ short swq[64 * 72], skv[64 * 72], skvs[64 * 72];
    __shared__ short wbuf[4][16 * 72];
    __shared__ float sks[128];
    __shared__ float sbq[64];

    // ---- one-time staging of this head's operand matrices ----
    {
        const short8* gq = reinterpret_cast<const short8*>(wqTb + (size_t)h * 4096);
        const short8* gk = reinterpret_cast<const short8*>(kvb + bh * 4096);
        const short8* gs = reinterpret_cast<const short8*>(kvsb + bh * 4096);
#pragma unroll
        for (int cc = 0; cc < 2; ++cc) {
            const int idx = t * 2 + cc;              // 0..511 short8 chunks
            const int row = idx >> 3, c8 = (idx & 7) * 8;
            *reinterpret_cast<short8*>(&swq [row * 72 + c8]) = gq[idx];
            *reinterpret_cast<short8*>(&skv [row * 72 + c8]) = gk[idx];
            *reinterpret_cast<short8*>(&skvs[row * 72 + c8]) = gs[idx];
        }
    }
    if (t < 128) sks[t] = ksums[bh * 128 + t];
    else if (t < 192) sbq[t - 128] = wq_b[h * 64 + (t - 128)];
    __syncthreads();

    float bq4[4], ksx4[4], kss4[4];
#pragma unroll
    for (int nt = 0; nt < 4; ++nt) {
        bq4[nt]  = sbq[nt * 16 + l15];
        ksx4[nt] = sks[nt * 16 + l15];
        kss4[nt] = sks[64 + nt * 16 + l15];
    }
    short* myb = &wbuf[w][0];
    const int s0w = sblk * 256 + w * 64;

    for (int ts = 0; ts < 4; ++ts) {
        const int srow0 = s0w + ts * 16;
        // ---- q A-frags (global, coalesced) ----
        const float* qp = query + ((size_t)b * SS + srow0 + l15) * 64 + q8;
        float4 f0 = *reinterpret_cast<const float4*>(qp);
        float4 f1 = *reinterpret_cast<const float4*>(qp + 4);
        float4 f2 = *reinterpret_cast<const float4*>(qp + 32);
        float4 f3 = *reinterpret_cast<const float4*>(qp + 36);
        short8 aq0 = cvt8(f0, f1), aq1 = cvt8(f2, f3);

        // ---- Q projection (B from LDS) ----
        f32x4 cq[4];
#pragma unroll
        for (int nt = 0; nt < 4; ++nt) cq[nt] = (f32x4){0.f, 0.f, 0.f, 0.f};
#pragma unroll
        for (int nt = 0; nt < 4; ++nt) {
            short8 b0 = *reinterpret_cast<const short8*>(&swq[(nt * 16 + l15) * 72 + q8]);
            short8 b1 = *reinterpret_cast<const short8*>(&swq[(nt * 16 + l15) * 72 + 32 + q8]);
            cq[nt] = MFMA(aq0, b0, cq[nt]);
            cq[nt] = MFMA(aq1, b1, cq[nt]);
        }

        // ---- elu + denominator + q' -> wave-private LDS ([s][x]) ----
        float ccr[4], dp[4] = {0.f, 0.f, 0.f, 0.f};
#pragma unroll
        for (int r = 0; r < 4; ++r) {
            float ph = PI_C * (float)(srow0 + q4 + r) * (1.f / 4096.f);
            ccr[r] = __cosf(ph) + __sinf(ph);
        }
#pragma unroll
        for (int nt = 0; nt < 4; ++nt) {
#pragma unroll
            for (int r = 0; r < 4; ++r) {
                float qv = elu1(cq[nt][r] + bq4[nt]);
                dp[r] = fmaf(qv, fmaf(ccr[r], kss4[nt], ksx4[nt]), dp[r]);
                myb[(q4 + r) * 72 + nt * 16 + l15] = f2bf(qv);
            }
        }
#pragma unroll
        for (int m = 1; m <= 8; m <<= 1) {
#pragma unroll
            for (int r = 0; r < 4; ++r) dp[r] += __shfl_xor(dp[r], m);
        }
        float invd[4];
#pragma unroll
        for (int r = 0; r < 4; ++r) invd[r] = 1.f / (dp[r] + 1e-5f);

        // ---- q' A-frags (wave-private; lgkmcnt-ordered, no barrier) ----
        short8 a0 = *reinterpret_cast<const short8*>(&myb[l15 * 72 + q8]);
        short8 a1 = *reinterpret_cast<const short8*>(&myb[l15 * 72 + 32 + q8]);

        // ---- numerator GEMMs (B from LDS) ----
        f32x4 ckv[4], ckvs[4];
#pragma unroll
        for (int nt = 0; nt < 4; ++nt) {
            ckv[nt]  = (f32x4){0.f, 0.f, 0.f, 0.f};
            ckvs[nt] = (f32x4){0.f, 0.f, 0.f, 0.f};
        }
#pragma unroll
        for (int nt = 0; nt < 4; ++nt) {
            short8 b0 = *reinterpret_cast<const short8*>(&skv [(nt * 16 + l15) * 72 + q8]);
            short8 b1 = *reinterpret_cast<const short8*>(&skv [(nt * 16 + l15) * 72 + 32 + q8]);
            short8 c0 = *reinterpret_cast<const short8*>(&skvs[(nt * 16 + l15) * 72 + q8]);
            short8 c1 = *reinterpret_cast<const short8*>(&skvs[(nt * 16 + l15) * 72 + 32 + q8]);
            ckv[nt]  = MFMA(a0, b0, ckv[nt]);
            ckv[nt]  = MFMA(a1, b1, ckv[nt]);
            ckvs[nt] = MFMA(a0, c0, ckvs[nt]);
            ckvs[nt] = MFMA(a1, c1, ckvs[nt]);
        }

        // ---- combine + transpose O to [s][z] (wave-private) ----
#pragma unroll
        for (int nt = 0; nt < 4; ++nt) {
#pragma unroll
            for (int r = 0; r < 4; ++r) {
                float o = fmaf(ccr[r], ckvs[nt][r], ckv[nt][r]) * invd[r];
                myb[(q4 + r) * 72 + nt * 16 + l15] = f2bf(o);
            }
        }
        // ---- coalesced bf16 store: O[b][h][s][z] ----
        {
            short8 o0 = *reinterpret_cast<const short8*>(&myb[l15 * 72 + q4 * 4]);
            short8 o1 = *reinterpret_cast<const short8*>(&myb[l15 * 72 + q4 * 4 + 8]);
            short* op = Obuf + (bh * SS + srow0 + l15) * 64 + q4 * 4;
            *reinterpret_cast<short8*>(op)     = o0;
            *reinterpret_cast<short8*>(op + 8) = o1;
        }
    }
}

// ---------------------------------------------------------------------------
// k_dense: out[16384 x 64] = O[16384 x 1024] @ dense_w + bias.
// O layout [b][h][s][z] makes A-frags directly loadable (k = h outer, z inner);
// B-frags use wdTb's existing per-head [c][z] layout.
__global__ __launch_bounds__(256, 4) void k_dense(
    const short* __restrict__ Obuf, const short* __restrict__ wdTb,
    const float* __restrict__ dense_b, float* __restrict__ out)
{
    const int blk = blockIdx.x;                 // 0..255 (64 rows each)
    const int t = threadIdx.x, w = t >> 6, l = t & 63;
    const int l15 = l & 15, q8 = (l >> 4) * 8, q4 = (l >> 4) * 4;
    const int r0 = blk * 64 + w * 16;           // wave's global row base
    const int b = r0 >> 12;
    const int s0 = r0 & 4095;

    f32x4 cd[4];
#pragma unroll
    for (int nt = 0; nt < 4; ++nt) cd[nt] = (f32x4){0.f, 0.f, 0.f, 0.f};

    for (int h = 0; h < HH; ++h) {
        const short* Oh  = Obuf + (((size_t)(b * HH + h)) * SS + s0 + l15) * 64;
        const short* wdh = wdTb + (size_t)h * 4096;
#pragma unroll
        for (int zh = 0; zh < 2; ++zh) {
            short8 a = *reinterpret_cast<const short8*>(Oh + zh * 32 + q8);
#pragma unroll
            for (int nt = 0; nt < 4; ++nt) {
                short8 bb = *reinterpret_cast<const short8*>(
                    wdh + (nt * 16 + l15) * 64 + zh * 32 + q8);
                cd[nt] = MFMA(a, bb, cd[nt]);
            }
        }
    }
    // bias + fp32 store
#pragma unroll
    for (int nt = 0; nt < 4; ++nt) {
        const int c = nt * 16 + l15;
        const float bias = dense_b[c];
#pragma unroll
        for (int r = 0; r < 4; ++r)
            out[((size_t)b * SS + s0 + q4 + r) * 64 + c] = cd[nt][r] + bias;
    }
}

// ---------------------------------------------------------------------------
extern "C" void kernel_launch(void* const* d_in, const int* in_sizes, int n_in,
                              void* d_out, int out_size, void* d_ws, size_t ws_size,
                              hipStream_t stream) {
    const float* query   = (const float*)d_in[0];
    const float* key     = (const float*)d_in[1];
    const float* value   = (const float*)d_in[2];
    // d_in[3] attn_mask unused
    const float* wq_w    = (const float*)d_in[4];
    const float* wq_b    = (const float*)d_in[5];
    const float* wk_w    = (const float*)d_in[6];
    const float* wk_b    = (const float*)d_in[7];
    const float* wv_w    = (const float*)d_in[8];
    const float* wv_b    = (const float*)d_in[9];
    const float* dense_w = (const float*)d_in[10];
    const float* dense_b = (const float*)d_in[11];
    float* out = (float*)d_out;

    char* ws = (char*)d_ws;
    short* wT    = (short*)(ws);             // wq|wk|wv|wd, 65536 shorts each
    short* kvb   = (short*)(ws + 524288);
    short* kvsb  = (short*)(ws + 1048576);
    float* ksums = (float*)(ws + 1572864);
    float* pkv   = (float*)(ws + 1605632);
    float* pkvs  = (float*)(ws + 9994240);
    float* pks   = (float*)(ws + 18382848);
    short* Obuf  = (short*)(ws + 1605632);   // overlay: pkv/pkvs/pks dead after k_reduce
    short* wqTb  = wT;
    short* wkTb  = wT + 65536;
    short* wvTb  = wT + 131072;
    short* wdTb  = wT + 196608;

    hipLaunchKernelGGL(k_prep, dim3(16, 4), dim3(256), 0, stream,
                       wq_w, wk_w, wv_w, dense_w, wT);
    hipLaunchKernelGGL(k_phase1, dim3(8, HH, BB), dim3(256), 0, stream,
                       key, value, wk_b, wv_b, wkTb, wvTb, pkv, pkvs, pks);
    hipLaunchKernelGGL(k_reduce, dim3(520), dim3(256), 0, stream,
                       pkv, pkvs, pks, kvb, kvsb, ksums);
    hipLaunchKernelGGL(k_attn, dim3(16, HH, BB), dim3(256), 0, stream,
                       query, wq_b, wqTb, kvb, kvsb, ksums, Obuf);
    hipLaunchKernelGGL(k_dense, dim3(256), dim3(256), 0, stream,
                       Obuf, wdTb, dense_b, out);
}